// Round 10
// baseline (545.555 us; speedup 1.0000x reference)
//
#include <hip/hip_runtime.h>

typedef __bf16 bf16;
typedef __bf16 bf16x8 __attribute__((ext_vector_type(8)));
typedef float floatx4 __attribute__((ext_vector_type(4)));

#define BATCH 128
#define SEQ   2048
#define HID   128
#define TWOH  256
#define CH    128
#define NCH   16

__device__ __forceinline__ float fast_tanh(float x) {
    float e = __builtin_amdgcn_exp2f(2.88539008177793f * x);
    return 1.0f - 2.0f * __builtin_amdgcn_rcpf(e + 1.0f);
}
__device__ __forceinline__ float fast_sigmoid(float x) {
    return __builtin_amdgcn_rcpf(1.0f + __builtin_amdgcn_exp2f(-1.44269504088896f * x));
}

union PK4 { unsigned long long u; bf16 h[4]; };

// ---- one-time f32 -> bf16 conversion of Wx2h (both layers, plain layout) ----
__global__ __launch_bounds__(256) void convert_w_k(const float* __restrict__ W,
                                                   bf16* __restrict__ Wb) {
    int i = blockIdx.x * 256 + threadIdx.x;   // 16384 float4 groups
    float4 v = ((const float4*)W)[i];
    PK4 pk;
    pk.h[0] = (bf16)v.x; pk.h[1] = (bf16)v.y;
    pk.h[2] = (bf16)v.z; pk.h[3] = (bf16)v.w;
    ((unsigned long long*)Wb)[i] = pk.u;
}

// In-tile inclusive prefix over the 128 rows of a chunk, one column set.
__device__ __forceinline__ void tile_prefix(const float g[4][4], float pref[4][4],
                                            float* stripe_tot, int quad, int l16) {
    float mibase = 0.f;
    #pragma unroll
    for (int mi = 0; mi < 4; ++mi) {
        float s0 = g[mi][0];
        float s1 = s0 + g[mi][1];
        float s2 = s1 + g[mi][2];
        float s3 = s2 + g[mi][3];
        float tot = s3, xq = tot;
        float t = __shfl_up(xq, 16);
        if (quad >= 1) xq += t;
        t = __shfl_up(xq, 32);
        if (quad >= 2) xq += t;
        float excl = mibase + xq - tot;
        pref[mi][0] = excl + s0;
        pref[mi][1] = excl + s1;
        pref[mi][2] = excl + s2;
        pref[mi][3] = excl + s3;
        mibase += __shfl(xq, 48 + l16);   // quad-3 inclusive total
    }
    *stripe_tot = mibase;
}

// ===========================================================================
// ONE BLOCK = ONE BATCH. The time-scan dependency is per-batch, so each block
// walks its batch's chunks sequentially, carrying the running column-prefix
// offsets in registers -- no scan kernels, no T buffer, no cross-block sync.
// Intra-chunk geometry is the round-3-verified one: 512 threads = 8 waves,
// wr = wid>>2 (row 64-stripe), wc = wid&3 (col 32-stripe per half).
// C row = wr*64+mi*16+quad*4+rr, col = half*128+wc*32+ni*16+l16.
// Per chunk: As=x -> GEMM0 -> tanh -> prefix+run-offset -> h0 -> As,
//            Ws: W0 -> W1 (register-preloaded swap) -> GEMM1 -> tanh ->
//            prefix+run-offset -> h1 -> fc dot -> masked loss (reg accum).
// EARLY-EXIT: only ceil(xlen/128) chunks processed (verified r5/r7).
// ===========================================================================
__global__ __launch_bounds__(512, 2) void batch_k(const float* __restrict__ x,
                                                  const bf16* __restrict__ Wb,
                                                  const float* __restrict__ Wfc,
                                                  const int* __restrict__ xlen,
                                                  const float* __restrict__ xlab,
                                                  float* __restrict__ out) {
    __shared__ bf16 As[128 * 128];          // 32 KB: x tile, then h0 tile
    __shared__ bf16 Ws[256 * 128];          // 64 KB: current layer's full W
    __shared__ float aux[2][2][128];        // [alt][stripe][col] totals
    __shared__ float zbuf[4][128][2];
    __shared__ float red[2];

    const int tid  = threadIdx.x;
    const int lane = tid & 63;
    const int wid  = tid >> 6;
    const int wr   = wid >> 2;
    const int wc   = wid & 3;
    const int quad = lane >> 4;
    const int l16  = lane & 15;
    const int bb   = blockIdx.x;
    const int xl   = xlen[bb];
    const int nact = (xl + CH - 1) >> 7;    // <= 16
    if (nact == 0) return;                  // uniform

    // fc weights for this thread's columns (layer-1 output rows 0,1)
    float wfc0[2], wfc1[2];
    #pragma unroll
    for (int ni = 0; ni < 2; ++ni) {
        int col = wc * 32 + ni * 16 + l16;
        wfc0[ni] = Wfc[2 * HID + col];
        wfc1[ni] = Wfc[3 * HID + col];
    }
    const float xlb = xlab[bb];

    float offr[2][2][2];                    // [layer][half][ni] running offsets
    #pragma unroll
    for (int a = 0; a < 2; ++a)
        #pragma unroll
        for (int b = 0; b < 2; ++b) { offr[a][b][0] = 0.f; offr[a][b][1] = 0.f; }
    float lsum = 0.f;

    // initial prefetch: x chunk 0 and W layer-0
    float4 xr[8];
    uint4  wreg[8];
    {
        const float4* A4 = (const float4*)(x + (size_t)bb * SEQ * HID);
        #pragma unroll
        for (int it = 0; it < 8; ++it) xr[it] = A4[it * 512 + tid];
        const uint4* W8 = (const uint4*)Wb;
        #pragma unroll
        for (int it = 0; it < 8; ++it) wreg[it] = W8[it * 512 + tid];
    }

    for (int c = 0; c < nact; ++c) {
        __syncthreads();                    // prior chunk's As/Ws/zbuf readers done
        // stage x -> As (swizzled, from prefetch regs)
        #pragma unroll
        for (int it = 0; it < 8; ++it) {
            int i  = it * 512 + tid;
            int r  = i >> 5;
            int c4 = i & 31;
            int g = c4 >> 1, hf = c4 & 1;
            float4 v = xr[it];
            PK4 pk;
            pk.h[0] = (bf16)v.x; pk.h[1] = (bf16)v.y;
            pk.h[2] = (bf16)v.z; pk.h[3] = (bf16)v.w;
            *(unsigned long long*)&As[r * 128 + ((g ^ (r & 7)) << 3) + (hf << 2)] = pk.u;
        }
        // stage W layer-0 -> Ws (swizzled, from preload regs)
        #pragma unroll
        for (int it = 0; it < 8; ++it) {
            int i = it * 512 + tid;
            int r = i >> 4;
            int g = i & 15;
            *(uint4*)&Ws[r * 128 + ((g ^ (r & 7)) << 3)] = wreg[it];
        }
        // prefetch next x chunk
        if (c + 1 < nact) {
            const float4* A4 =
                (const float4*)(x + ((size_t)bb * SEQ + (size_t)(c + 1) * CH) * HID);
            #pragma unroll
            for (int it = 0; it < 8; ++it) xr[it] = A4[it * 512 + tid];
        }
        // preload W layer-1 (L2-hot)
        {
            const uint4* W8 = (const uint4*)(Wb + (size_t)TWOH * HID);
            #pragma unroll
            for (int it = 0; it < 8; ++it) wreg[it] = W8[it * 512 + tid];
        }
        __syncthreads();                    // As(x) + Ws(W0) ready

        float p1[2][4][4];                  // per-layer half-0 global prefixes

        #pragma unroll
        for (int l = 0; l < 2; ++l) {
            #pragma unroll
            for (int h = 0; h < 2; ++h) {
                // ---- GEMM: A from As, B rows h*128.. from Ws ----
                floatx4 acc[4][2];
                #pragma unroll
                for (int a = 0; a < 4; ++a)
                    #pragma unroll
                    for (int b2 = 0; b2 < 2; ++b2)
                        acc[a][b2] = (floatx4){0.f, 0.f, 0.f, 0.f};
                #pragma unroll
                for (int s = 0; s < 4; ++s) {
                    int kg = s * 4 + quad;
                    bf16x8 af[4], bfr[2];
                    #pragma unroll
                    for (int mi = 0; mi < 4; ++mi) {
                        int r = wr * 64 + mi * 16 + l16;
                        af[mi] = *(const bf16x8*)&As[r * 128 + ((kg ^ (r & 7)) << 3)];
                    }
                    #pragma unroll
                    for (int ni = 0; ni < 2; ++ni) {
                        int n8 = h * 128 + wc * 32 + ni * 16 + l16;
                        bfr[ni] = *(const bf16x8*)&Ws[n8 * 128 + ((kg ^ (n8 & 7)) << 3)];
                    }
                    #pragma unroll
                    for (int mi = 0; mi < 4; ++mi)
                        #pragma unroll
                        for (int ni = 0; ni < 2; ++ni)
                            acc[mi][ni] = __builtin_amdgcn_mfma_f32_16x16x32_bf16(
                                af[mi], bfr[ni], acc[mi][ni], 0, 0, 0);
                }

                // ---- tanh + in-tile prefix + running-offset exchange ----
                float g2[2][4][4];
                #pragma unroll
                for (int mi = 0; mi < 4; ++mi)
                    #pragma unroll
                    for (int ni = 0; ni < 2; ++ni)
                        #pragma unroll
                        for (int rr = 0; rr < 4; ++rr)
                            g2[ni][mi][rr] = fast_tanh(acc[mi][ni][rr]);

                float pref[2][4][4], st[2];
                #pragma unroll
                for (int ni = 0; ni < 2; ++ni)
                    tile_prefix(g2[ni], pref[ni], &st[ni], quad, l16);
                const int a = (l * 2 + h) & 1;
                if (quad == 0) {
                    #pragma unroll
                    for (int ni = 0; ni < 2; ++ni)
                        aux[a][wr][wc * 32 + ni * 16 + l16] = st[ni];
                }
                __syncthreads();            // aux exchange

                float offuse[2];
                #pragma unroll
                for (int ni = 0; ni < 2; ++ni) {
                    int col = wc * 32 + ni * 16 + l16;
                    float s0t = aux[a][0][col];
                    float tot = s0t + aux[a][1][col];
                    offuse[ni] = offr[l][h][ni] + (wr ? s0t : 0.f);
                    offr[l][h][ni] += tot;  // running chunk-prefix update
                }

                if (h == 0) {
                    // save global-inclusive s1n prefixes for this layer
                    #pragma unroll
                    for (int ni = 0; ni < 2; ++ni)
                        #pragma unroll
                        for (int mi = 0; mi < 4; ++mi)
                            #pragma unroll
                            for (int rr = 0; rr < 4; ++rr)
                                p1[ni][mi][rr] = pref[ni][mi][rr] + offuse[ni];
                } else if (l == 0) {
                    // h0 -> As (all GEMM0 reads done: aux barrier passed)
                    #pragma unroll
                    for (int ni = 0; ni < 2; ++ni) {
                        int col = wc * 32 + ni * 16 + l16;
                        int gsw = col >> 3, rem = col & 7;
                        #pragma unroll
                        for (int mi = 0; mi < 4; ++mi)
                            #pragma unroll
                            for (int rr = 0; rr < 4; ++rr) {
                                int row = wr * 64 + mi * 16 + quad * 4 + rr;
                                float hv = pref[ni][mi][rr] + offuse[ni] -
                                           fmaxf(p1[ni][mi][rr], 0.f) * g2[ni][mi][rr];
                                As[row * 128 + ((gsw ^ (row & 7)) << 3) + rem] = (bf16)hv;
                            }
                    }
                    // swap Ws: W1 from preload regs (Ws(W0) reads done)
                    #pragma unroll
                    for (int it = 0; it < 8; ++it) {
                        int i = it * 512 + tid;
                        int r = i >> 4;
                        int g = i & 15;
                        *(uint4*)&Ws[r * 128 + ((g ^ (r & 7)) << 3)] = wreg[it];
                    }
                    // preload W0 for next chunk
                    if (c + 1 < nact) {
                        const uint4* W8 = (const uint4*)Wb;
                        #pragma unroll
                        for (int it = 0; it < 8; ++it) wreg[it] = W8[it * 512 + tid];
                    }
                    __syncthreads();        // As(h0) + Ws(W1) ready
                } else {
                    // layer 1 half 1: h1 -> fc dot -> zbuf
                    #pragma unroll
                    for (int mi = 0; mi < 4; ++mi)
                        #pragma unroll
                        for (int rr = 0; rr < 4; ++rr) {
                            float z0 = 0.f, z1 = 0.f;
                            #pragma unroll
                            for (int ni = 0; ni < 2; ++ni) {
                                float hv = pref[ni][mi][rr] + offuse[ni] -
                                           fmaxf(p1[ni][mi][rr], 0.f) * g2[ni][mi][rr];
                                z0 += hv * wfc0[ni];
                                z1 += hv * wfc1[ni];
                            }
                            z0 += __shfl_xor(z0, 1); z1 += __shfl_xor(z1, 1);
                            z0 += __shfl_xor(z0, 2); z1 += __shfl_xor(z1, 2);
                            z0 += __shfl_xor(z0, 4); z1 += __shfl_xor(z1, 4);
                            z0 += __shfl_xor(z0, 8); z1 += __shfl_xor(z1, 8);
                            if (l16 == 0) {
                                int row = wr * 64 + mi * 16 + quad * 4 + rr;
                                zbuf[wc][row][0] = z0;
                                zbuf[wc][row][1] = z1;
                            }
                        }
                    __syncthreads();        // zbuf ready
                    if (tid < 128) {
                        int row = tid;
                        float z0 = zbuf[0][row][0] + zbuf[1][row][0] +
                                   zbuf[2][row][0] + zbuf[3][row][0];
                        float z1 = zbuf[0][row][1] + zbuf[1][row][1] +
                                   zbuf[2][row][1] + zbuf[3][row][1];
                        float o1 = fast_sigmoid(z1 - z0);
                        float sg = fast_sigmoid(o1);
                        float d  = xlb - sg;
                        if (c * CH + row < xl) lsum += d * d;
                    }
                }
            }
        }
    }

    // ---- final loss reduce (tid<128 hold per-row sums) ----
    lsum += __shfl_xor(lsum, 1);
    lsum += __shfl_xor(lsum, 2);
    lsum += __shfl_xor(lsum, 4);
    lsum += __shfl_xor(lsum, 8);
    lsum += __shfl_xor(lsum, 16);
    lsum += __shfl_xor(lsum, 32);
    if (lane == 0 && wid < 2) red[wid] = lsum;
    __syncthreads();
    if (tid == 0) atomicAdd(out, red[0] + red[1]);
}

extern "C" void kernel_launch(void* const* d_in, const int* in_sizes, int n_in,
                              void* d_out, int out_size, void* d_ws, size_t ws_size,
                              hipStream_t stream) {
    const float* x    = (const float*)d_in[0];
    const int*   xlen = (const int*)d_in[1];
    const float* xlab = (const float*)d_in[2];
    const float* Wx2h = (const float*)d_in[3];  // [2,256,128] f32
    const float* Wfc  = (const float*)d_in[4];  // [2,2,128] f32
    float* out = (float*)d_out;

    bf16* Wb = (bf16*)d_ws;                     // 128 KiB

    hipMemsetAsync(d_out, 0, sizeof(float), stream);
    convert_w_k<<<64, 256, 0, stream>>>(Wx2h, Wb);
    batch_k<<<BATCH, 512, 0, stream>>>(x, Wb, Wfc, xlen, xlab, out);
}

// Round 11
// 320.305 us; speedup vs baseline: 1.7032x; 1.7032x over previous
//
#include <hip/hip_runtime.h>

typedef __bf16 bf16;
typedef __bf16 bf16x8 __attribute__((ext_vector_type(8)));
typedef float floatx4 __attribute__((ext_vector_type(4)));

#define BATCH 128
#define SEQ   2048
#define HID   128
#define TWOH  256
#define CH    128
#define NCH   16
#define MTOT  (BATCH * SEQ)    // 262144

__device__ __forceinline__ float fast_tanh(float x) {
    float e = __builtin_amdgcn_exp2f(2.88539008177793f * x);
    return 1.0f - 2.0f * __builtin_amdgcn_rcpf(e + 1.0f);
}
__device__ __forceinline__ float fast_sigmoid(float x) {
    return __builtin_amdgcn_rcpf(1.0f + __builtin_amdgcn_exp2f(-1.44269504088896f * x));
}

union PK4 { unsigned long long u; bf16 h[4]; };
union PK8 { uint4 u; bf16 h[8]; };

// ---- one-time f32 -> bf16 conversion of Wx2h (both layers) ----
__global__ __launch_bounds__(256) void convert_w_k(const float* __restrict__ W,
                                                   bf16* __restrict__ Wb) {
    int i = blockIdx.x * 256 + threadIdx.x;   // 16384 float4 groups
    float4 v = ((const float4*)W)[i];
    PK4 pk;
    pk.h[0] = (bf16)v.x; pk.h[1] = (bf16)v.y;
    pk.h[2] = (bf16)v.z; pk.h[3] = (bf16)v.w;
    ((unsigned long long*)Wb)[i] = pk.u;
}

// In-tile inclusive prefix over the 128 rows of a chunk, one column set.
__device__ __forceinline__ void tile_prefix(const float g[4][4], float pref[4][4],
                                            float* stripe_tot, int quad, int l16) {
    float mibase = 0.f;
    #pragma unroll
    for (int mi = 0; mi < 4; ++mi) {
        float s0 = g[mi][0];
        float s1 = s0 + g[mi][1];
        float s2 = s1 + g[mi][2];
        float s3 = s2 + g[mi][3];
        float tot = s3, xq = tot;
        float t = __shfl_up(xq, 16);
        if (quad >= 1) xq += t;
        t = __shfl_up(xq, 32);
        if (quad >= 2) xq += t;
        float excl = mibase + xq - tot;
        pref[mi][0] = excl + s0;
        pref[mi][1] = excl + s1;
        pref[mi][2] = excl + s2;
        pref[mi][3] = excl + s3;
        mibase += __shfl(xq, 48 + l16);   // quad-3 inclusive total
    }
    *stripe_tot = mibase;
}

// ===========================================================================
// Geometry (round-3-verified): 512 threads = 8 waves, wr = wid>>2 (row
// 64-stripe), wc = wid&3 (col 32-stripe per half).
// C row = wr*64+mi*16+quad*4+rr, col = half*128+wc*32+ni*16+l16.
// tanh fragments stored to T in per-thread layout (coalesced uint4).
// EARLY-EXIT (r5/r7/r9-verified): chunks with cc*128 >= xlen[bb] skipped.
// K-SPLIT (r9-verified neutral, kept): Bs[128][64] K-halves, LDS 50KB.
// SELF-SCAN (r5-verified, this round): P0/P1 hold RAW chunk sums; each
// consumer block sums its cc predecessors itself (ascending cp = identical
// FP order to the old scan kernel). Unconditional loads + select: inactive
// chunks' unwritten P entries are discarded by cndmask, never arithmetic.
// ===========================================================================

// ---- K1: layer-0 GEMM; store tanh fragments + RAW per-chunk column sums ----
__global__ __launch_bounds__(512, 4) void l0_k(const float* __restrict__ x,
                                               const bf16* __restrict__ Wb,
                                               uint4* __restrict__ T,
                                               float* __restrict__ Pout,
                                               const int* __restrict__ xlen) {
    __shared__ bf16 As[128 * 128];          // 32 KB  (x tile)
    __shared__ bf16 Bs[128 * 64];           // 16 KB  (W K-half)
    __shared__ float psum[512];             // 2 KB

    const int tid  = threadIdx.x;
    const int lane = tid & 63;
    const int wid  = tid >> 6;
    const int wr   = wid >> 2;
    const int wc   = wid & 3;
    const int quad = lane >> 4;
    const int l16  = lane & 15;
    const long blk = blockIdx.x;
    const int  bb  = (int)(blk >> 4);
    const int  cc  = (int)(blk & 15);
    if ((cc << 7) >= xlen[bb]) return;      // uniform early-exit, before barriers

    const long rowBase = blk * 128;

    // stage x chunk (f32 -> bf16, swizzled into As[128][128], 16 groups of 8)
    {
        const float4* A4 = (const float4*)(x + rowBase * HID);
        #pragma unroll
        for (int it = 0; it < 8; ++it) {
            int i  = it * 512 + tid;
            int r  = i >> 5;
            int c4 = i & 31;
            float4 v = A4[i];
            int g = c4 >> 1, hf = c4 & 1;
            PK4 pk;
            pk.h[0] = (bf16)v.x; pk.h[1] = (bf16)v.y;
            pk.h[2] = (bf16)v.z; pk.h[3] = (bf16)v.w;
            *(unsigned long long*)&As[r * 128 + ((g ^ (r & 7)) << 3) + (hf << 2)] = pk.u;
        }
    }

    #pragma unroll
    for (int half = 0; half < 2; ++half) {
        floatx4 acc[4][2];
        #pragma unroll
        for (int a = 0; a < 4; ++a)
            #pragma unroll
            for (int b2 = 0; b2 < 2; ++b2) acc[a][b2] = (floatx4){0.f, 0.f, 0.f, 0.f};

        #pragma unroll
        for (int kp = 0; kp < 2; ++kp) {
            if (half + kp) __syncthreads();  // prior Bs reads done
            // stage W quarter (half, kp): rows 0..127 of this half, cols kp*64..+64
            {
                const uint4* W8 = (const uint4*)(Wb + (size_t)half * 128 * HID + kp * 64);
                #pragma unroll
                for (int it = 0; it < 2; ++it) {
                    int i = it * 512 + tid;
                    int r = i >> 3;          // 0..127
                    int g = i & 7;           // col-group within K-half
                    uint4 v = W8[r * 16 + g];   // row stride = 128 bf16 = 16 uint4
                    *(uint4*)&Bs[r * 64 + ((g ^ (r & 7)) << 3)] = v;
                }
            }
            __syncthreads();                 // Bs ready (+As ready at first)

            #pragma unroll
            for (int kk2 = 0; kk2 < 2; ++kk2) {
                int kgl = kk2 * 4 + quad;    // local K-group in Bs (0..7)
                int kg  = kp * 8 + kgl;      // global K-group in As (0..15)
                bf16x8 af[4], bfr[2];
                #pragma unroll
                for (int mi = 0; mi < 4; ++mi) {
                    int r = wr * 64 + mi * 16 + l16;
                    af[mi] = *(const bf16x8*)&As[r * 128 + ((kg ^ (r & 7)) << 3)];
                }
                #pragma unroll
                for (int ni = 0; ni < 2; ++ni) {
                    int n = wc * 32 + ni * 16 + l16;
                    bfr[ni] = *(const bf16x8*)&Bs[n * 64 + ((kgl ^ (n & 7)) << 3)];
                }
                #pragma unroll
                for (int mi = 0; mi < 4; ++mi)
                    #pragma unroll
                    for (int ni = 0; ni < 2; ++ni)
                        acc[mi][ni] = __builtin_amdgcn_mfma_f32_16x16x32_bf16(
                            af[mi], bfr[ni], acc[mi][ni], 0, 0, 0);
            }
        }

        float g2[2][4][4];   // [ni][mi][rr]
        #pragma unroll
        for (int mi = 0; mi < 4; ++mi)
            #pragma unroll
            for (int ni = 0; ni < 2; ++ni)
                #pragma unroll
                for (int rr = 0; rr < 4; ++rr)
                    g2[ni][mi][rr] = fast_tanh(acc[mi][ni][rr]);

        // store tanh fragments (coalesced); overlaps next restage barrier
        #pragma unroll
        for (int mi = 0; mi < 4; ++mi) {
            PK8 p;
            #pragma unroll
            for (int rr = 0; rr < 4; ++rr) {
                p.h[rr]     = (bf16)g2[0][mi][rr];
                p.h[4 + rr] = (bf16)g2[1][mi][rr];
            }
            T[((blk * 2 + half) * 4 + mi) * 512 + tid] = p.u;
        }

        // per-column stripe sums
        #pragma unroll
        for (int ni = 0; ni < 2; ++ni) {
            float cs = 0.f;
            #pragma unroll
            for (int mi = 0; mi < 4; ++mi)
                #pragma unroll
                for (int rr = 0; rr < 4; ++rr) cs += g2[ni][mi][rr];
            cs += __shfl_xor(cs, 16);
            cs += __shfl_xor(cs, 32);
            if (quad == 0)
                psum[wr * 256 + half * 128 + wc * 32 + ni * 16 + l16] = cs;
        }
    }

    __syncthreads();
    if (tid < 256) Pout[(blk << 8) + tid] = psum[tid] + psum[256 + tid];
}

// ---- K2: self-scan P0 + reload tanh0 -> h0 in LDS; layer-1 GEMM; tanh1 ----
__global__ __launch_bounds__(512, 4) void l1_k(const bf16* __restrict__ Wb1,
                                               uint4* __restrict__ T,
                                               const float* __restrict__ P0,
                                               float* __restrict__ Pout,
                                               const int* __restrict__ xlen) {
    __shared__ bf16 As[128 * 128];          // h0 tile, 32 KB
    __shared__ bf16 Bs[128 * 64];           // 16 KB
    __shared__ float offP[256];             // exclusive chunk-prefix offsets
    __shared__ float auxp[128];
    __shared__ float psum[512];

    const int tid  = threadIdx.x;
    const int lane = tid & 63;
    const int wid  = tid >> 6;
    const int wr   = wid >> 2;
    const int wc   = wid & 3;
    const int quad = lane >> 4;
    const int l16  = lane & 15;
    const long blk = blockIdx.x;
    const int  bb  = (int)(blk >> 4);
    const int  cc  = (int)(blk & 15);
    if ((cc << 7) >= xlen[bb]) return;

    // self-scan: ascending cp = identical FP order to the old scan kernel.
    // Loads unconditional (always-valid memory); poison from inactive chunks
    // is discarded by the select, never touched arithmetically.
    float pv = 0.f;
    if (tid < 256) {
        #pragma unroll
        for (int cp = 0; cp < NCH - 1; ++cp) {
            float v = P0[(((long)(bb * NCH + cp)) << 8) + tid];
            pv += (cp < cc) ? v : 0.f;
        }
    }

    float p1[2][4][4];   // half-0 global-inclusive prefixes (s1n)

    // ---- half 0 of tanh0: prefix -> p1 ----
    {
        float g2[2][4][4];
        #pragma unroll
        for (int mi = 0; mi < 4; ++mi) {
            PK8 p;
            p.u = T[((blk * 2 + 0) * 4 + mi) * 512 + tid];
            #pragma unroll
            for (int rr = 0; rr < 4; ++rr) {
                g2[0][mi][rr] = (float)p.h[rr];
                g2[1][mi][rr] = (float)p.h[4 + rr];
            }
        }
        if (tid < 256) offP[tid] = pv;
        float pref[2][4][4], st[2];
        #pragma unroll
        for (int ni = 0; ni < 2; ++ni) {
            tile_prefix(g2[ni], pref[ni], &st[ni], quad, l16);
            if (wr == 0 && quad == 0) auxp[wc * 32 + ni * 16 + l16] = st[ni];
        }
        __syncthreads();   // offP + auxp ready
        #pragma unroll
        for (int ni = 0; ni < 2; ++ni) {
            int col = wc * 32 + ni * 16 + l16;
            float off = offP[col];
            if (wr) off += auxp[col];
            #pragma unroll
            for (int mi = 0; mi < 4; ++mi)
                #pragma unroll
                for (int rr = 0; rr < 4; ++rr)
                    p1[ni][mi][rr] = pref[ni][mi][rr] + off;
        }
    }
    __syncthreads();   // auxp reuse guard

    // ---- half 1 of tanh0: prefix -> h0 -> As (swizzled bf16) ----
    {
        float g2[2][4][4];
        #pragma unroll
        for (int mi = 0; mi < 4; ++mi) {
            PK8 p;
            p.u = T[((blk * 2 + 1) * 4 + mi) * 512 + tid];
            #pragma unroll
            for (int rr = 0; rr < 4; ++rr) {
                g2[0][mi][rr] = (float)p.h[rr];
                g2[1][mi][rr] = (float)p.h[4 + rr];
            }
        }
        float pref[2][4][4], st[2];
        #pragma unroll
        for (int ni = 0; ni < 2; ++ni) {
            tile_prefix(g2[ni], pref[ni], &st[ni], quad, l16);
            if (wr == 0 && quad == 0) auxp[wc * 32 + ni * 16 + l16] = st[ni];
        }
        __syncthreads();
        #pragma unroll
        for (int ni = 0; ni < 2; ++ni) {
            int col = wc * 32 + ni * 16 + l16;
            int gsw = col >> 3, rem = col & 7;
            float off = offP[128 + col];
            if (wr) off += auxp[col];
            #pragma unroll
            for (int mi = 0; mi < 4; ++mi)
                #pragma unroll
                for (int rr = 0; rr < 4; ++rr) {
                    int row = wr * 64 + mi * 16 + quad * 4 + rr;
                    float h = pref[ni][mi][rr] + off -
                              fmaxf(p1[ni][mi][rr], 0.f) * g2[ni][mi][rr];
                    As[row * 128 + ((gsw ^ (row & 7)) << 3) + rem] = (bf16)h;
                }
        }
    }

    // ---- layer-1 GEMM + tanh -> store tanh1 + column sums (K-split Bs) ----
    #pragma unroll
    for (int half = 0; half < 2; ++half) {
        floatx4 acc[4][2];
        #pragma unroll
        for (int a = 0; a < 4; ++a)
            #pragma unroll
            for (int b2 = 0; b2 < 2; ++b2) acc[a][b2] = (floatx4){0.f, 0.f, 0.f, 0.f};

        #pragma unroll
        for (int kp = 0; kp < 2; ++kp) {
            if (half + kp) __syncthreads();  // prior Bs reads done
            {
                const uint4* W8 = (const uint4*)(Wb1 + (size_t)half * 128 * HID + kp * 64);
                #pragma unroll
                for (int it = 0; it < 2; ++it) {
                    int i = it * 512 + tid;
                    int r = i >> 3;
                    int g = i & 7;
                    uint4 v = W8[r * 16 + g];
                    *(uint4*)&Bs[r * 64 + ((g ^ (r & 7)) << 3)] = v;
                }
            }
            __syncthreads();                 // Bs ready (+As h0-writes at first)

            #pragma unroll
            for (int kk2 = 0; kk2 < 2; ++kk2) {
                int kgl = kk2 * 4 + quad;
                int kg  = kp * 8 + kgl;
                bf16x8 af[4], bfr[2];
                #pragma unroll
                for (int mi = 0; mi < 4; ++mi) {
                    int r = wr * 64 + mi * 16 + l16;
                    af[mi] = *(const bf16x8*)&As[r * 128 + ((kg ^ (r & 7)) << 3)];
                }
                #pragma unroll
                for (int ni = 0; ni < 2; ++ni) {
                    int n = wc * 32 + ni * 16 + l16;
                    bfr[ni] = *(const bf16x8*)&Bs[n * 64 + ((kgl ^ (n & 7)) << 3)];
                }
                #pragma unroll
                for (int mi = 0; mi < 4; ++mi)
                    #pragma unroll
                    for (int ni = 0; ni < 2; ++ni)
                        acc[mi][ni] = __builtin_amdgcn_mfma_f32_16x16x32_bf16(
                            af[mi], bfr[ni], acc[mi][ni], 0, 0, 0);
            }
        }

        float g2[2][4][4];
        #pragma unroll
        for (int mi = 0; mi < 4; ++mi)
            #pragma unroll
            for (int ni = 0; ni < 2; ++ni)
                #pragma unroll
                for (int rr = 0; rr < 4; ++rr)
                    g2[ni][mi][rr] = fast_tanh(acc[mi][ni][rr]);

        #pragma unroll
        for (int mi = 0; mi < 4; ++mi) {
            PK8 p;
            #pragma unroll
            for (int rr = 0; rr < 4; ++rr) {
                p.h[rr]     = (bf16)g2[0][mi][rr];
                p.h[4 + rr] = (bf16)g2[1][mi][rr];
            }
            T[((blk * 2 + half) * 4 + mi) * 512 + tid] = p.u;
        }

        #pragma unroll
        for (int ni = 0; ni < 2; ++ni) {
            float cs = 0.f;
            #pragma unroll
            for (int mi = 0; mi < 4; ++mi)
                #pragma unroll
                for (int rr = 0; rr < 4; ++rr) cs += g2[ni][mi][rr];
            cs += __shfl_xor(cs, 16);
            cs += __shfl_xor(cs, 32);
            if (quad == 0)
                psum[wr * 256 + half * 128 + wc * 32 + ni * 16 + l16] = cs;
        }
    }

    __syncthreads();
    if (tid < 256) Pout[(blk << 8) + tid] = psum[tid] + psum[256 + tid];
}

// ---- K3: self-scan P1 + reload tanh1 -> h1 -> fc dot -> masked loss ----
__global__ __launch_bounds__(512, 4) void loss_k(const uint4* __restrict__ T,
                                                 const float* __restrict__ P1,
                                                 const float* __restrict__ Wfc,
                                                 const int* __restrict__ xlen,
                                                 const float* __restrict__ xlab,
                                                 float* __restrict__ out) {
    __shared__ float offP[256];
    __shared__ float auxp[128];
    __shared__ float zbuf[4][128][2];
    __shared__ float red[2];

    const int tid  = threadIdx.x;
    const int lane = tid & 63;
    const int wid  = tid >> 6;
    const int wr   = wid >> 2;
    const int wc   = wid & 3;
    const int quad = lane >> 4;
    const int l16  = lane & 15;
    const long blk = blockIdx.x;
    const int  bb  = (int)(blk >> 4);
    const int  cc  = (int)(blk & 15);
    if ((cc << 7) >= xlen[bb]) return;

    float pv = 0.f;
    if (tid < 256) {
        #pragma unroll
        for (int cp = 0; cp < NCH - 1; ++cp) {
            float v = P1[(((long)(bb * NCH + cp)) << 8) + tid];
            pv += (cp < cc) ? v : 0.f;
        }
    }

    float p1[2][4][4];

    // half 0: prefix -> p1
    {
        float g2[2][4][4];
        #pragma unroll
        for (int mi = 0; mi < 4; ++mi) {
            PK8 p;
            p.u = T[((blk * 2 + 0) * 4 + mi) * 512 + tid];
            #pragma unroll
            for (int rr = 0; rr < 4; ++rr) {
                g2[0][mi][rr] = (float)p.h[rr];
                g2[1][mi][rr] = (float)p.h[4 + rr];
            }
        }
        if (tid < 256) offP[tid] = pv;
        float pref[2][4][4], st[2];
        #pragma unroll
        for (int ni = 0; ni < 2; ++ni) {
            tile_prefix(g2[ni], pref[ni], &st[ni], quad, l16);
            if (wr == 0 && quad == 0) auxp[wc * 32 + ni * 16 + l16] = st[ni];
        }
        __syncthreads();   // offP + auxp ready
        #pragma unroll
        for (int ni = 0; ni < 2; ++ni) {
            int col = wc * 32 + ni * 16 + l16;
            float off = offP[col];
            if (wr) off += auxp[col];
            #pragma unroll
            for (int mi = 0; mi < 4; ++mi)
                #pragma unroll
                for (int rr = 0; rr < 4; ++rr)
                    p1[ni][mi][rr] = pref[ni][mi][rr] + off;
        }
    }
    __syncthreads();

    // half 1: prefix -> h1 -> fc dot
    {
        float g2[2][4][4];
        #pragma unroll
        for (int mi = 0; mi < 4; ++mi) {
            PK8 p;
            p.u = T[((blk * 2 + 1) * 4 + mi) * 512 + tid];
            #pragma unroll
            for (int rr = 0; rr < 4; ++rr) {
                g2[0][mi][rr] = (float)p.h[rr];
                g2[1][mi][rr] = (float)p.h[4 + rr];
            }
        }
        float pref[2][4][4], st[2];
        #pragma unroll
        for (int ni = 0; ni < 2; ++ni) {
            tile_prefix(g2[ni], pref[ni], &st[ni], quad, l16);
            if (wr == 0 && quad == 0) auxp[wc * 32 + ni * 16 + l16] = st[ni];
        }
        __syncthreads();

        float w0[2], w1[2], off[2];
        #pragma unroll
        for (int ni = 0; ni < 2; ++ni) {
            int col = wc * 32 + ni * 16 + l16;
            w0[ni] = Wfc[2 * HID + col];
            w1[ni] = Wfc[3 * HID + col];
            off[ni] = offP[128 + col];
            if (wr) off[ni] += auxp[col];
        }
        #pragma unroll
        for (int mi = 0; mi < 4; ++mi)
            #pragma unroll
            for (int rr = 0; rr < 4; ++rr) {
                float z0 = 0.f, z1 = 0.f;
                #pragma unroll
                for (int ni = 0; ni < 2; ++ni) {
                    float h = pref[ni][mi][rr] + off[ni] -
                              fmaxf(p1[ni][mi][rr], 0.f) * g2[ni][mi][rr];
                    z0 += h * w0[ni];
                    z1 += h * w1[ni];
                }
                z0 += __shfl_xor(z0, 1); z1 += __shfl_xor(z1, 1);
                z0 += __shfl_xor(z0, 2); z1 += __shfl_xor(z1, 2);
                z0 += __shfl_xor(z0, 4); z1 += __shfl_xor(z1, 4);
                z0 += __shfl_xor(z0, 8); z1 += __shfl_xor(z1, 8);
                if (l16 == 0) {
                    int row = wr * 64 + mi * 16 + quad * 4 + rr;
                    zbuf[wc][row][0] = z0;
                    zbuf[wc][row][1] = z1;
                }
            }
    }

    __syncthreads();
    float lsum = 0.f;
    if (tid < 128) {
        int row = tid;
        float z0 = zbuf[0][row][0] + zbuf[1][row][0] + zbuf[2][row][0] + zbuf[3][row][0];
        float z1 = zbuf[0][row][1] + zbuf[1][row][1] + zbuf[2][row][1] + zbuf[3][row][1];
        float o1 = fast_sigmoid(z1 - z0);
        float sg = fast_sigmoid(o1);
        float d = xlab[bb] - sg;
        if (cc * CH + row < xlen[bb]) lsum = d * d;
        lsum += __shfl_xor(lsum, 1);
        lsum += __shfl_xor(lsum, 2);
        lsum += __shfl_xor(lsum, 4);
        lsum += __shfl_xor(lsum, 8);
        lsum += __shfl_xor(lsum, 16);
        lsum += __shfl_xor(lsum, 32);
        if (lane == 0) red[wid] = lsum;
    }
    __syncthreads();
    if (tid == 0) atomicAdd(out, red[0] + red[1]);
}

extern "C" void kernel_launch(void* const* d_in, const int* in_sizes, int n_in,
                              void* d_out, int out_size, void* d_ws, size_t ws_size,
                              hipStream_t stream) {
    const float* x    = (const float*)d_in[0];
    const int*   xlen = (const int*)d_in[1];
    const float* xlab = (const float*)d_in[2];
    const float* Wx2h = (const float*)d_in[3];  // [2,256,128] f32
    const float* Wfc  = (const float*)d_in[4];  // [2,2,128] f32
    float* out = (float*)d_out;

    char* ws = (char*)d_ws;
    uint4* T  = (uint4*)ws;                                   // 128 MiB tanh frags
    float* P0 = (float*)(ws + (size_t)MTOT * TWOH * 2);       // 2 MiB raw chunk sums
    float* P1 = P0 + (size_t)BATCH * NCH * TWOH;              // 2 MiB
    bf16*  Wb = (bf16*)(P1 + (size_t)BATCH * NCH * TWOH);     // 128 KiB

    hipMemsetAsync(d_out, 0, sizeof(float), stream);
    convert_w_k<<<64, 256, 0, stream>>>(Wx2h, Wb);

    l0_k<<<MTOT / 128, 512, 0, stream>>>(x, Wb, T, P0, xlen);
    l1_k<<<MTOT / 128, 512, 0, stream>>>(Wb + (size_t)TWOH * HID, T, P0, P1, xlen);
    loss_k<<<MTOT / 128, 512, 0, stream>>>(T, P1, Wfc, xlen, xlab, out);
}